// Round 3
// baseline (265.840 us; speedup 1.0000x reference)
//
#include <hip/hip_runtime.h>

// ---------------------------------------------------------------------------
// Compile-time Clifford algebra tables (N_GEN=6, DIM=64), replicating the
// reference _build_algebra() exactly: blades sorted by (popcount, value).
// ---------------------------------------------------------------------------
namespace alg {
constexpr int pc(int v) { int c = 0; while (v) { c += v & 1; v >>= 1; } return c; }
constexpr int swap_sign_i(int a, int b) {
  int s = 0; a >>= 1;
  while (a) { s += pc(a & b); a >>= 1; }
  return (s & 1) ? -1 : 1;
}
struct Tables {
  int blade[64]; int index[64]; int cls[64];
  int itab[64][64]; int sgn[64][64]; int ct[64][64];
  constexpr Tables() : blade{}, index{}, cls{}, itab{}, sgn{}, ct{} {
    int pos = 0;
    for (int g = 0; g <= 6; ++g)
      for (int b = 0; b < 64; ++b)
        if (pc(b) == g) { blade[pos] = b; index[b] = pos; ++pos; }
    for (int i = 0; i < 64; ++i) cls[i] = pc(blade[i]) & 3;
    for (int J = 0; J < 64; ++J)
      for (int K = 0; K < 64; ++K) {
        int bj = blade[J], bk = blade[K], bi = bj ^ bk;
        int I = index[bi];
        itab[J][K] = I;
        sgn[J][K] = swap_sign_i(bi, bk);
        ct[J][K] = cls[I] * 16 + cls[J] * 4 + cls[K];
      }
  }
};
constexpr Tables T{};
}  // namespace alg

__device__ __forceinline__ float rfl(float v) {
  return __uint_as_float(__builtin_amdgcn_readfirstlane(__float_as_uint(v)));
}

// ---------------------------------------------------------------------------
// Hand-rolled grid barrier. Safe because grid=256 blocks at 1 block/CU
// (capacity is 2 blocks/CU) => all blocks co-resident by construction.
// __threadfence() = agent-scope fence: L2 writeback/invalidate handles
// cross-XCD visibility (G16); atomicAdd on global is device-scope (m20).
// Counters are zeroed by hipMemsetAsync before launch (graph-capture-legal).
// ---------------------------------------------------------------------------
__device__ __forceinline__ void gbar(unsigned int* c, unsigned int target) {
  __syncthreads();
  __threadfence();  // release: publish this block's global writes
  if (threadIdx.x == 0) {
    atomicAdd(c, 1u);
    while (atomicAdd(c, 0u) < target) __builtin_amdgcn_s_sleep(1);
  }
  __syncthreads();
  __threadfence();  // acquire: invalidate stale cache lines before reading
}

// ---------------------------------------------------------------------------
// Product body (phase C inner): 16 j's per wave, then LDS transpose + store.
// Wave-synchronous (ot is wave-private; lgkmcnt(0) between write and read).
// ---------------------------------------------------------------------------
template <int JW>
__device__ __forceinline__ void prod_body(
    const float* __restrict__ xv, const float* __restrict__ rv,
    const float* __restrict__ gl, float* __restrict__ out,
    float* __restrict__ ot, int n, int bc, int lane) {
  float acc[16];
#pragma unroll
  for (int jj = 0; jj < 16; ++jj) acc[jj] = 0.f;
#pragma unroll
  for (int k = 0; k < 64; ++k) {
#pragma unroll
    for (int jj = 0; jj < 16; ++jj) {
      const int j = JW * 16 + jj;
      const int ii = alg::T.itab[j][k];
      const int tt = alg::T.ct[j][k];
      float t = xv[ii] * rv[k];
      acc[jj] = fmaf(alg::T.sgn[j][k] > 0 ? gl[tt] : -gl[tt], t, acc[jj]);
    }
  }
#pragma unroll
  for (int jj = 0; jj < 16; ++jj) ot[jj * 68 + lane] = acc[jj];
  __builtin_amdgcn_s_waitcnt(0);  // lgkmcnt(0)
#pragma unroll
  for (int p = 0; p < 16; ++p) {
    int j = lane & 15, br = p * 4 + (lane >> 4);
    out[(bc + br) * 8192 + n * 64 + JW * 16 + j] = ot[j * 68 + br];
  }
}

// ---------------------------------------------------------------------------
// ONE kernel, 256 blocks x 512 threads (1 block/CU), plain launch + gbar.
//   Phase A: transpose x -> xT[i][m][b] (2 tiles/block in parallel halves);
//            Wt[c][m][n]; g[n][64].
//   Phase B: round-0 klin verbatim: block=(i,bc), 8 waves x 16 n, LDS-staged
//            x-slice, wave-uniform scalar (s_load) float4 weight broadcasts.
//   Phase C: two kprod units/block (s = t>>8). x staged DIRECTLY from input
//            ([b][65]-padded LDS), xr staged, gating in-register, product.
// LDS: max(A: 8320, B: 8192, C: 2x8384) = 16768 floats = 67 KB < 160 KB.
// ---------------------------------------------------------------------------
__global__ __launch_bounds__(512, 2) void kfused(
    const float* __restrict__ x, const float* __restrict__ wlin,
    const float* __restrict__ wgp, const int* __restrict__ pidx, int P,
    const float* __restrict__ blin, const float* __restrict__ an,
    float* __restrict__ xT, float* __restrict__ xrT,
    float* __restrict__ Wt, float* __restrict__ g,
    unsigned int* __restrict__ bar, float* __restrict__ out) {
  __shared__ float smem[16768];  // 67 KB, re-carved per phase
  int bid = blockIdx.x;          // 256
  int t = threadIdx.x;           // 512

  // ---------------- Phase A: prep ----------------
  {
    int s = t >> 8, tl = t & 255;
    int u = bid * 2 + s;  // 0..511 transpose units
    float* tile = smem + s * 4160;
    int m = u >> 2, bc = (u & 3) << 6;
    int lane = tl & 63, row = tl >> 6;
#pragma unroll
    for (int p = 0; p < 16; ++p) {
      int b = p * 4 + row;
      tile[lane * 65 + b] = x[(bc + b) * 8192 + m * 64 + lane];
    }
    __syncthreads();
#pragma unroll
    for (int p = 0; p < 16; ++p) {
      int il = p * 4 + row;
      xT[il * 32768 + m * 256 + bc + lane] = tile[il * 65 + lane];
    }
    if (t < 256) {  // Wt: 65536 elems = 256 blocks x 256
      int id = bid * 256 + t;
      int n = id & 127, mm = (id >> 7) & 127, c = id >> 14;
      Wt[c * 16384 + mm * 128 + n] = wlin[n * 512 + mm * 4 + c];
    }
    if (t < 32) {  // g: 8192 elems = 256 blocks x 32
      int id = bid * 32 + t;
      int n = id >> 6, tt = id & 63;
      int ti = tt >> 4, tj = (tt >> 2) & 3, tk = tt & 3;
      float v = 0.f;
      for (int p = 0; p < P; ++p)
        if (pidx[p * 3] == ti && pidx[p * 3 + 1] == tj && pidx[p * 3 + 2] == tk)
          v = wgp[n * P + p];
      g[n * 64 + tt] = v;
    }
  }
  gbar(bar, 256);

  // ---------------- Phase B: linear (round-0 klin, verbatim shape) --------
  {
    float* xs = smem;  // [m][b] 128*64 = 32 KB
    int i = bid >> 2;
    int bc = (bid & 3) << 6;
    int ci = alg::T.cls[i];
    {
      int b = t & 63, m0 = t >> 6;  // m0 in 0..7
      const float* src = xT + i * 32768 + bc + b;
#pragma unroll
      for (int r = 0; r < 16; ++r) {
        int m = m0 * 16 + r;
        xs[m * 64 + b] = src[m * 256];
      }
    }
    __syncthreads();

    int w = __builtin_amdgcn_readfirstlane(t >> 6);  // uniform wave id 0..7
    int lane = t & 63;
    const float4* wp4 = (const float4*)Wt + ci * 4096 + w * 4;
    float acc[16];
#pragma unroll
    for (int q = 0; q < 16; ++q) acc[q] = 0.f;

#pragma unroll 4
    for (int m = 0; m < 128; ++m) {
      float xv = xs[m * 64 + lane];
#pragma unroll
      for (int q = 0; q < 4; ++q) {
        float4 wv = wp4[m * 32 + q];  // uniform address -> s_load broadcast
        acc[q * 4 + 0] = fmaf(xv, wv.x, acc[q * 4 + 0]);
        acc[q * 4 + 1] = fmaf(xv, wv.y, acc[q * 4 + 1]);
        acc[q * 4 + 2] = fmaf(xv, wv.z, acc[q * 4 + 2]);
        acc[q * 4 + 3] = fmaf(xv, wv.w, acc[q * 4 + 3]);
      }
    }
    if (i == 0) {
#pragma unroll
      for (int q = 0; q < 16; ++q) acc[q] += blin[w * 16 + q];
    }
#pragma unroll
    for (int q = 0; q < 16; ++q)
      xrT[(w * 16 + q) * 16384 + i * 256 + bc + lane] = acc[q];
  }
  gbar(bar + 32, 256);

  // ---------------- Phase C: gating + geometric product -------------------
  {
    int s = t >> 8, tl = t & 255;
    int u = bid * 2 + s;  // 0..511 product units
    int n = u >> 2;
    int bc = (u & 3) << 6;
    float* base = smem + s * 8384;
    float* xs2 = base;         // [b][65] padded, 4160 floats
    float* rs = base + 4160;   // [b][65] padded, 4160 floats
    int w = __builtin_amdgcn_readfirstlane((tl >> 6) & 3);  // 0..3 per unit
    int lane = tl & 63;

    // stage x DIRECTLY (row-contiguous in i): lanes = i, coalesced 256B rows
    {
      int i = tl & 63, b0 = tl >> 6;
      const float* sx = x + n * 64 + i;
#pragma unroll
      for (int r = 0; r < 16; ++r) {
        int b = r * 4 + b0;
        xs2[b * 65 + i] = sx[(bc + b) * 8192];
      }
    }
    // stage xr (contiguous in b): lanes = b
    {
      int b = tl & 63, i0 = tl >> 6;
      const float* sr = xrT + n * 16384 + bc + b;
#pragma unroll
      for (int r = 0; r < 16; ++r) {
        int i = i0 * 16 + r;
        rs[b * 65 + i] = sr[i * 256];
      }
    }
    __syncthreads();

    // per-thread register copies (b128, conflict-free via +1 pad)
    float xv[64], rv[64];
#pragma unroll
    for (int i = 0; i < 64; ++i) xv[i] = xs2[lane * 65 + i];
#pragma unroll
    for (int i = 0; i < 64; ++i) rv[i] = rs[lane * 65 + i];

    float gl[64];
#pragma unroll
    for (int q = 0; q < 64; ++q) gl[q] = rfl(g[n * 64 + q]);

    // gating (per lane = per b)
    float sq[4] = {0.f, 0.f, 0.f, 0.f};
#pragma unroll
    for (int i = 0; i < 64; ++i) {
      const int c = alg::T.cls[i];
      sq[c] = fmaf(rv[i], rv[i], sq[c]);
    }
    float r[4];
#pragma unroll
    for (int c = 0; c < 4; ++c) {
      float a = rfl(an[n * 4 + c]);
      float sig = 1.f / (1.f + __expf(-a));
      float gate = sig * (sqrtf(sq[c]) - 1.f) + 1.f;
      r[c] = 1.f / (gate + 1e-6f);
    }
#pragma unroll
    for (int i = 0; i < 64; ++i) rv[i] *= r[alg::T.cls[i]];

    __syncthreads();  // staging dead; re-carve unit's LDS as output scratch
    float* ot = base + w * 1088;  // 4 x 1088 = 4352 <= 8384, in-bounds

    switch (w) {
      case 0: prod_body<0>(xv, rv, gl, out, ot, n, bc, lane); break;
      case 1: prod_body<1>(xv, rv, gl, out, ot, n, bc, lane); break;
      case 2: prod_body<2>(xv, rv, gl, out, ot, n, bc, lane); break;
      case 3: prod_body<3>(xv, rv, gl, out, ot, n, bc, lane); break;
    }
  }
}

// ---------------------------------------------------------------------------
extern "C" void kernel_launch(void* const* d_in, const int* in_sizes, int n_in,
                              void* d_out, int out_size, void* d_ws, size_t ws_size,
                              hipStream_t stream) {
  (void)n_in; (void)out_size; (void)ws_size;
  const float* x    = (const float*)d_in[0];
  const float* wgp  = (const float*)d_in[1];
  const float* wlin = (const float*)d_in[2];
  const float* blin = (const float*)d_in[3];
  const float* an   = (const float*)d_in[4];
  const int*   pidx = (const int*)d_in[7];
  int P = in_sizes[7] / 3;

  float* ws  = (float*)d_ws;
  float* xT  = ws;                // 2,097,152 floats (8 MB)
  float* xrT = ws + 2097152;      // 2,097,152 floats (8 MB)
  float* Wt  = ws + 4194304;      // 65,536 floats (256 KB)
  float* g   = ws + 4259840;      // 8,192 floats (32 KB)
  unsigned int* bar = (unsigned int*)(ws + 4268032);  // 2 counters, 128B apart

  hipMemsetAsync(bar, 0, 256, stream);  // capture-legal (stream op)
  kfused<<<256, 512, 0, stream>>>(x, wlin, wgp, pidx, P, blin, an, xT, xrT,
                                  Wt, g, bar, (float*)d_out);
}

// Round 4
// 108.607 us; speedup vs baseline: 2.4477x; 2.4477x over previous
//
#include <hip/hip_runtime.h>
#include <hip/hip_bf16.h>

// ---------------------------------------------------------------------------
// Compile-time Clifford algebra tables (N_GEN=6, DIM=64), replicating the
// reference _build_algebra() exactly: blades sorted by (popcount, value).
// ---------------------------------------------------------------------------
namespace alg {
constexpr int pc(int v) { int c = 0; while (v) { c += v & 1; v >>= 1; } return c; }
constexpr int swap_sign_i(int a, int b) {
  int s = 0; a >>= 1;
  while (a) { s += pc(a & b); a >>= 1; }
  return (s & 1) ? -1 : 1;
}
struct Tables {
  int blade[64]; int index[64]; int cls[64];
  int itab[64][64]; int sgn[64][64]; int ct[64][64];
  constexpr Tables() : blade{}, index{}, cls{}, itab{}, sgn{}, ct{} {
    int pos = 0;
    for (int g = 0; g <= 6; ++g)
      for (int b = 0; b < 64; ++b)
        if (pc(b) == g) { blade[pos] = b; index[b] = pos; ++pos; }
    for (int i = 0; i < 64; ++i) cls[i] = pc(blade[i]) & 3;
    for (int J = 0; J < 64; ++J)
      for (int K = 0; K < 64; ++K) {
        int bj = blade[J], bk = blade[K], bi = bj ^ bk;
        int I = index[bi];
        itab[J][K] = I;
        sgn[J][K] = swap_sign_i(bi, bk);
        ct[J][K] = cls[I] * 16 + cls[J] * 4 + cls[K];
      }
  }
};
constexpr Tables T{};
}  // namespace alg

typedef float vf2 __attribute__((ext_vector_type(2)));

__device__ __forceinline__ float rfl(float v) {
  return __uint_as_float(__builtin_amdgcn_readfirstlane(__float_as_uint(v)));
}

__device__ __forceinline__ vf2 pkfma(vf2 a, vf2 b, vf2 c) {
#if __has_builtin(__builtin_elementwise_fma)
  return __builtin_elementwise_fma(a, b, c);
#else
  vf2 r; r.x = fmaf(a.x, b.x, c.x); r.y = fmaf(a.y, b.y, c.y); return r;
#endif
}

// ---------------------------------------------------------------------------
// Kernel 1 (prep): blocks 0..511  : transpose x[b][m][i] -> xT[i][m][b]
//                  blocks 512..767: Wt[c][m][n] = w_lin[n][m][c]
//                  blocks 768..799: g[n][ci*16+cj*4+ck] from w_gp/path_idx
// (xT now feeds ONLY klin; kprod stages x directly.)
// ---------------------------------------------------------------------------
__global__ __launch_bounds__(256) void kprep(
    const float* __restrict__ x, const float* __restrict__ wlin,
    const float* __restrict__ wgp, const int* __restrict__ pidx, int P,
    float* __restrict__ xT, float* __restrict__ Wt, float* __restrict__ g) {
  int bid = blockIdx.x;
  if (bid < 512) {
    __shared__ float tile[64 * 65];
    int m = bid >> 2, bc = (bid & 3) << 6;
    int lane = threadIdx.x & 63, row = threadIdx.x >> 6;
#pragma unroll
    for (int p = 0; p < 16; ++p) {
      int b = p * 4 + row;
      tile[lane * 65 + b] = x[(bc + b) * 8192 + m * 64 + lane];
    }
    __syncthreads();
#pragma unroll
    for (int p = 0; p < 16; ++p) {
      int il = p * 4 + row;
      xT[il * 32768 + m * 256 + bc + lane] = tile[il * 65 + lane];
    }
  } else if (bid < 768) {
    int id = (bid - 512) * 256 + threadIdx.x;  // 0..65535
    int n = id & 127, m = (id >> 7) & 127, c = id >> 14;
    Wt[c * 16384 + m * 128 + n] = wlin[n * 512 + m * 4 + c];
  } else {
    int id = (bid - 768) * 256 + threadIdx.x;  // 0..8191
    int n = id >> 6, t = id & 63;
    int ti = t >> 4, tj = (t >> 2) & 3, tk = t & 3;
    float v = 0.f;
    for (int p = 0; p < P; ++p)
      if (pidx[p * 3] == ti && pidx[p * 3 + 1] == tj && pidx[p * 3 + 2] == tk)
        v = wgp[n * P + p];
    g[n * 64 + t] = v;
  }
}

// ---------------------------------------------------------------------------
// Kernel 2 (linear): xr[b,n,i] = sum_m x[b,m,i]*Wt[cls_i][m][n]  (+b_lin at i=0)
// Round-1 verified shape: 1024 threads = 16 waves, one 32 KB LDS x-slice,
// wave-uniform scalar (s_load) float2 weight broadcasts + packed FMA.
// ---------------------------------------------------------------------------
__global__ __launch_bounds__(1024) void klin(
    const float* __restrict__ xT, const float* __restrict__ Wt,
    const float* __restrict__ blin, float* __restrict__ xrT) {
  __shared__ float xs[128 * 64];  // [m][b], 32 KB
  int bid = blockIdx.x;           // 256 blocks: (i in 0..63) x (bc in 0..3)
  int i = bid >> 2;
  int bc = (bid & 3) << 6;
  int ci = alg::T.cls[i];
  int t = threadIdx.x;
  {
    int b = t & 63, m0 = t >> 6;  // m0 in 0..15
    const float* src = xT + i * 32768 + bc + b;
#pragma unroll
    for (int r = 0; r < 8; ++r) {
      int m = m0 * 8 + r;
      xs[m * 64 + b] = src[m * 256];
    }
  }
  __syncthreads();

  int w = __builtin_amdgcn_readfirstlane(t >> 6);  // uniform wave id 0..15
  int lane = t & 63;                               // = b - bc
  const vf2* wp2 = (const vf2*)Wt + ci * 8192 + w * 4;
  vf2 acc[4];
#pragma unroll
  for (int p = 0; p < 4; ++p) acc[p] = (vf2)(0.f);

#pragma unroll 4
  for (int m = 0; m < 128; ++m) {
    float xv = xs[m * 64 + lane];
    vf2 xv2 = {xv, xv};
#pragma unroll
    for (int p = 0; p < 4; ++p) {
      vf2 wv = wp2[m * 64 + p];   // uniform address -> scalar load
      acc[p] = pkfma(xv2, wv, acc[p]);
    }
  }
  if (i == 0) {
#pragma unroll
    for (int p = 0; p < 4; ++p) {
      acc[p].x += blin[w * 8 + 2 * p];
      acc[p].y += blin[w * 8 + 2 * p + 1];
    }
  }
#pragma unroll
  for (int p = 0; p < 4; ++p) {
    int n0 = w * 8 + 2 * p;
    xrT[n0 * 16384 + i * 256 + bc + lane] = acc[p].x;
    xrT[(n0 + 1) * 16384 + i * 256 + bc + lane] = acc[p].y;
  }
}

// ---------------------------------------------------------------------------
// Kernel 3 (product): fused gating + geometric product.
// CHANGED vs round 1: stages x DIRECTLY from the input tensor (row-contiguous
// in i => coalesced 256 B rows; [b][65]-padded LDS => conflict-free writes
// and conflict-free b128 register copies). Drops the 8 MB xT re-read.
// This staging logic is byte-identical to round-3's passing phase C.
// ---------------------------------------------------------------------------
template <int JW>
__device__ __forceinline__ void prod_body(
    const float* __restrict__ xv, const float* __restrict__ rv,
    const float* __restrict__ gl, float* __restrict__ out,
    float* __restrict__ ot, int n, int bc, int lane) {
  float acc[16];
#pragma unroll
  for (int jj = 0; jj < 16; ++jj) acc[jj] = 0.f;
#pragma unroll
  for (int k = 0; k < 64; ++k) {
#pragma unroll
    for (int jj = 0; jj < 16; ++jj) {
      const int j = JW * 16 + jj;
      const int ii = alg::T.itab[j][k];
      const int tt = alg::T.ct[j][k];
      float t = xv[ii] * rv[k];
      acc[jj] = fmaf(alg::T.sgn[j][k] > 0 ? gl[tt] : -gl[tt], t, acc[jj]);
    }
  }
  // transpose 16x64 tile through wave-private LDS region (wave-synchronous)
#pragma unroll
  for (int jj = 0; jj < 16; ++jj) ot[jj * 68 + lane] = acc[jj];
  __builtin_amdgcn_s_waitcnt(0);  // lgkmcnt(0)
#pragma unroll
  for (int p = 0; p < 16; ++p) {
    int j = lane & 15, br = p * 4 + (lane >> 4);
    out[(bc + br) * 8192 + n * 64 + JW * 16 + j] = ot[j * 68 + br];
  }
}

__global__ __launch_bounds__(256, 2) void kprod(
    const float* __restrict__ x, const float* __restrict__ xr,
    const float* __restrict__ g, const float* __restrict__ an,
    float* __restrict__ out) {
  __shared__ float smem[8384];   // 33.5 KB explicit union
  float* xs2 = smem;             // [b][65] padded, 4160 floats
  float* rs = smem + 4160;       // [b][65] padded, 4160 floats (tot 8320)
  int bid = blockIdx.x;          // 512 blocks: (n in 0..127) x (bc in 0..3)
  int n = bid >> 2;
  int bc = (bid & 3) << 6;
  int t = threadIdx.x;
  int w = __builtin_amdgcn_readfirstlane(t >> 6);  // uniform wave id
  int lane = t & 63;                               // = b - bc

  // stage x DIRECTLY (row-contiguous in i): lanes = i, coalesced 256B rows
  {
    int i = t & 63, b0 = t >> 6;
    const float* sx = x + n * 64 + i;
#pragma unroll
    for (int r = 0; r < 16; ++r) {
      int b = r * 4 + b0;
      xs2[b * 65 + i] = sx[(bc + b) * 8192];
    }
  }
  // stage xr (contiguous in b): lanes = b
  {
    int b = t & 63, i0 = t >> 6;
    const float* sr = xr + n * 16384 + bc + b;
#pragma unroll
    for (int r = 0; r < 16; ++r) {
      int i = i0 * 16 + r;
      rs[b * 65 + i] = sr[i * 256];
    }
  }
  __syncthreads();

  // per-thread register copies (b128, conflict-free via +1 pad)
  float xv[64], rv[64];
#pragma unroll
  for (int i = 0; i < 64; ++i) xv[i] = xs2[lane * 65 + i];
#pragma unroll
  for (int i = 0; i < 64; ++i) rv[i] = rs[lane * 65 + i];

  float gl[64];
#pragma unroll
  for (int q = 0; q < 64; ++q) gl[q] = rfl(g[n * 64 + q]);

  // gating (per lane = per b)
  float s[4] = {0.f, 0.f, 0.f, 0.f};
#pragma unroll
  for (int i = 0; i < 64; ++i) {
    const int c = alg::T.cls[i];
    s[c] = fmaf(rv[i], rv[i], s[c]);
  }
  float r[4];
#pragma unroll
  for (int c = 0; c < 4; ++c) {
    float a = rfl(an[n * 4 + c]);
    float sig = 1.f / (1.f + __expf(-a));
    float gate = sig * (sqrtf(s[c]) - 1.f) + 1.f;
    r[c] = 1.f / (gate + 1e-6f);
  }
#pragma unroll
  for (int i = 0; i < 64; ++i) rv[i] *= r[alg::T.cls[i]];

  __syncthreads();  // staging data now dead; re-carve smem as output scratch
  float* ot = smem + w * 1088;   // 4 x 1088 = 4352 floats <= 8384, in-bounds

  switch (w) {
    case 0: prod_body<0>(xv, rv, gl, out, ot, n, bc, lane); break;
    case 1: prod_body<1>(xv, rv, gl, out, ot, n, bc, lane); break;
    case 2: prod_body<2>(xv, rv, gl, out, ot, n, bc, lane); break;
    case 3: prod_body<3>(xv, rv, gl, out, ot, n, bc, lane); break;
  }
}

// ---------------------------------------------------------------------------
extern "C" void kernel_launch(void* const* d_in, const int* in_sizes, int n_in,
                              void* d_out, int out_size, void* d_ws, size_t ws_size,
                              hipStream_t stream) {
  (void)n_in; (void)out_size; (void)ws_size;
  const float* x    = (const float*)d_in[0];
  const float* wgp  = (const float*)d_in[1];
  const float* wlin = (const float*)d_in[2];
  const float* blin = (const float*)d_in[3];
  const float* an   = (const float*)d_in[4];
  const int*   pidx = (const int*)d_in[7];
  int P = in_sizes[7] / 3;

  float* ws  = (float*)d_ws;
  float* xT  = ws;                // 2,097,152 floats (8 MB)
  float* xrT = ws + 2097152;      // 2,097,152 floats (8 MB)
  float* Wt  = ws + 4194304;      // 65,536 floats (256 KB)
  float* g   = ws + 4259840;      // 8,192 floats (32 KB)

  kprep<<<800, 256, 0, stream>>>(x, wlin, wgp, pidx, P, xT, Wt, g);
  klin<<<256, 1024, 0, stream>>>(xT, Wt, blin, xrT);
  kprod<<<512, 256, 0, stream>>>(x, xrT, g, an, (float*)d_out);
}